// Round 8
// baseline (481.775 us; speedup 1.0000x reference)
//
#include <hip/hip_runtime.h>
#include <cmath>

// ---- problem constants ----
constexpr int Bb  = 512;
constexpr int Cc  = 12;
constexpr int Ww  = 4;
constexpr int Ff  = 512;
constexpr int Mx  = Bb * Ww * Cc;   // 24576

typedef __attribute__((ext_vector_type(8))) short bf16x8;
typedef __attribute__((ext_vector_type(4))) float f32x4;

__device__ __forceinline__ float sigm(float v) { return 1.f / (1.f + expf(-v)); }
__device__ __forceinline__ float b2f(ushort u) { union { float f; unsigned i; } v; v.i = ((unsigned)u) << 16; return v.f; }
__device__ __forceinline__ ushort f2b(float f) {
    union { float f; unsigned i; } v; v.f = f;
    unsigned r = v.i + 0x7FFFu + ((v.i >> 16) & 1u);
    return (ushort)(r >> 16);
}
// fast branch-free transcendentals (v_exp_f32 is native 2^x; v_rcp_f32 ~1ulp)
__device__ __forceinline__ float fsigm(float v) {
    return __builtin_amdgcn_rcpf(1.f + __builtin_amdgcn_exp2f(v * -1.44269504f));
}
__device__ __forceinline__ float ftanh(float v) {
    return 1.f - 2.f * __builtin_amdgcn_rcpf(1.f + __builtin_amdgcn_exp2f(v * 2.88539008f));
}
__device__ __forceinline__ void async16(const ushort* g, ushort* l) {
    __builtin_amdgcn_global_load_lds(
        (const __attribute__((address_space(1))) unsigned int*)g,
        (__attribute__((address_space(3))) unsigned int*)l, 16, 0, 0);
}

// =============== generic bf16 MFMA GEMM ===============
// C[M,N] = A[M,K] @ Bt[N,K]^T.  Block 128x128, 4 waves.
__global__ __launch_bounds__(256) void mfma_gemm(
    const ushort* __restrict__ A, const ushort* __restrict__ Bt,
    float* __restrict__ Cf, ushort* __restrict__ Cb,
    const float* __restrict__ colBias,
    int N, int K, int kLen, int MN, int gridY)
{
    __shared__ ushort As[128 * 64], Bs[128 * 64];
    const int tid = threadIdx.x;
    const int ln = tid & 63, wv = tid >> 6;
    const int l = blockIdx.x;
    const int by = l % gridY, bx = l / gridY, bz = blockIdx.y;
    const int srow = ln >> 3;
    const int kslot = (ln & 7) ^ srow;
    const int rowA0 = by * 128 + wv * 32;
    const int rowB0 = bx * 128 + wv * 32;
    const ushort* ga = A  + (long)(rowA0 + srow) * K + bz * kLen + kslot * 8;
    const ushort* gb = Bt + (long)(rowB0 + srow) * K + bz * kLen + kslot * 8;
    ushort* la = As + wv * 32 * 64;
    ushort* lb = Bs + wv * 32 * 64;
    const int rbase = (wv >> 1) * 64, cbase = (wv & 1) * 64;
    const int mrow = ln & 15, quad = ln >> 4;

    f32x4 acc[4][4] = {};

    for (int kc = 0; kc < kLen; kc += 64) {
        #pragma unroll
        for (int i = 0; i < 4; ++i) {
            async16(ga + (long)(i * 8) * K, la + i * 8 * 64);
            async16(gb + (long)(i * 8) * K, lb + i * 8 * 64);
        }
        ga += 64; gb += 64;
        __syncthreads();
        #pragma unroll
        for (int s = 0; s < 2; ++s) {
            const int sw = (((s << 2) + quad) ^ (ln & 7)) << 3;
            bf16x8 af[4], bf[4];
            #pragma unroll
            for (int i = 0; i < 4; ++i)
                af[i] = *(const bf16x8*)(As + (rbase + i * 16 + mrow) * 64 + sw);
            #pragma unroll
            for (int j = 0; j < 4; ++j)
                bf[j] = *(const bf16x8*)(Bs + (cbase + j * 16 + mrow) * 64 + sw);
            #pragma unroll
            for (int i = 0; i < 4; ++i)
                #pragma unroll
                for (int j = 0; j < 4; ++j)
                    acc[i][j] = __builtin_amdgcn_mfma_f32_16x16x32_bf16(bf[j], af[i], acc[i][j], 0, 0, 0);
        }
        __syncthreads();
    }

    const int gr0 = by * 128 + rbase + mrow;
    const int gc0 = bx * 128 + cbase + quad * 4;
    if (Cb) {
        #pragma unroll
        for (int i = 0; i < 4; ++i) {
            const long rowoff = (long)(gr0 + i * 16) * N;
            #pragma unroll
            for (int j = 0; j < 4; ++j) {
                float c0 = 0.f, c1 = 0.f, c2 = 0.f, c3 = 0.f;
                if (colBias) {
                    const float4 cb4 = *(const float4*)(colBias + gc0 + j * 16);
                    c0 = cb4.x; c1 = cb4.y; c2 = cb4.z; c3 = cb4.w;
                }
                union { ushort u[4]; uint2 v; } pk;
                pk.u[0] = f2b(acc[i][j][0] + c0);
                pk.u[1] = f2b(acc[i][j][1] + c1);
                pk.u[2] = f2b(acc[i][j][2] + c2);
                pk.u[3] = f2b(acc[i][j][3] + c3);
                *(uint2*)&Cb[rowoff + gc0 + j * 16] = pk.v;
            }
        }
    } else {
        float* Co = Cf + (long)bz * MN;
        #pragma unroll
        for (int i = 0; i < 4; ++i) {
            const long rowoff = (long)(gr0 + i * 16) * N;
            #pragma unroll
            for (int j = 0; j < 4; ++j)
                *(f32x4*)&Co[rowoff + gc0 + j * 16] = acc[i][j];
        }
    }
}

// =============== persistent GRU recurrence (v7: 32-row x 48-col waves, half Bw traffic) ===============
// v6 structure (register-direct A, region h exchange, read-only LDS Bw,
// block-level barrier w/ single tid-0 poller) with the intra-block work
// partition changed: 8 waves = 4 row-groups (rg) x 2 col-groups (cg).
// Wave (rg,cg): rows (2rg..2rg+1)*16, features cg*16..+16 of ALL 3 gates
// (B-tiles jt = g*2+cg). Each B-frag read feeds 2 row-tiles -> Bw ds_reads
// per wave per step 96 -> 48 (LDS stream was the largest per-step cost).
// h-region byte layout is IDENTICAL to v6; only who-writes-what changes.
__global__ __launch_bounds__(512, 1) void gru_persist(
    const ushort* __restrict__ xW, const ushort* __restrict__ whhB,
    const float* __restrict__ bih, const float* __restrict__ bhh,
    ushort* __restrict__ h0, ushort* __restrict__ h1,
    ushort* __restrict__ G, unsigned* __restrict__ bar)
{
    __shared__ ushort Bw[8 * 96 * 64];     // 96 KB: Whh slice, [kc][96][64] k-swizzled
    const int tid = threadIdx.x, ln = tid & 63, wv = tid >> 6;
    const int mb = blockIdx.x & 15, fb = blockIdx.x >> 4;
    const int srow = ln >> 3, kslot = (ln & 7) ^ srow;
    const int mrow = ln & 15, quad = ln >> 4;
    const int rg = wv >> 1, cg = wv & 1;   // 4 row-groups x 2 col-groups

    // ---- load Whh slice once: rows g*512 + fb*32 + fc, layout [kc][96][64] ----
    #pragma unroll
    for (int i = 0; i < 12; ++i) {
        const int rgx = i * 8 + wv;                // 0..95
        const int kc6 = rgx / 12, rgi = rgx - kc6 * 12;
        const int r0 = rgi * 8, r = r0 + srow;
        const int g = r >> 5, fc = r & 31;
        async16(whhB + (long)(g * 512 + fb * 32 + fc) * 512 + kc6 * 64 + kslot * 8,
                Bw + (kc6 * 96 + r0) * 64);
    }

    // ---- hoist biases: this wave covers features f0..f0+3 (all gates) ----
    const int f0 = fb * 32 + cg * 16 + quad * 4;
    float br[4], bz[4], bni[4], bnh[4];
    {
        const float4 bir = *(const float4*)(bih + f0);
        const float4 biz = *(const float4*)(bih + 512 + f0);
        const float4 bin = *(const float4*)(bih + 1024 + f0);
        const float4 bhr = *(const float4*)(bhh + f0);
        const float4 bhz = *(const float4*)(bhh + 512 + f0);
        const float4 bhn = *(const float4*)(bhh + 1024 + f0);
        br[0] = bir.x + bhr.x; br[1] = bir.y + bhr.y; br[2] = bir.z + bhr.z; br[3] = bir.w + bhr.w;
        bz[0] = biz.x + bhz.x; bz[1] = biz.y + bhz.y; bz[2] = biz.z + bhz.z; bz[3] = biz.w + bhz.w;
        bni[0] = bin.x; bni[1] = bin.y; bni[2] = bin.z; bni[3] = bin.w;
        bnh[0] = bhn.x; bnh[1] = bhn.y; bnh[2] = bhn.z; bnh[3] = bhn.w;
    }
    __syncthreads();   // Bw resident (compiler drains vmcnt before s_barrier); read-only after

    const int n0 = mb * 128 + (rg * 2 + 0) * 16 + mrow;   // row-tile 0
    const int n1 = n0 + 16;                               // row-tile 1
    unsigned* cptr = bar + mb * 16;        // 64B-spaced per-group counter

    // consumer a-load geometry (same region format as v6)
    const int aoff = (quad >> 1) * 256 + mrow * 16 + (quad & 1) * 8;
    const long rb0 = ((long)(mb * 8 + rg * 2 + 0) * 16) * 512;
    const long rb1 = ((long)(mb * 8 + rg * 2 + 1) * 16) * 512;
    // producer store: region (mb, 2rg+rt, fb), offset cg*256 + mrow*16 + quad*4
    const int sb0 = ((mb * 8 + rg * 2 + 0) * 16 + fb) * 512 + cg * 256 + mrow * 16 + quad * 4;
    const int sb1 = ((mb * 8 + rg * 2 + 1) * 16 + fb) * 512 + cg * 256 + mrow * 16 + quad * 4;

    uint2 hprev[2]; hprev[0].x = 0u; hprev[0].y = 0u; hprev[1] = hprev[0];

    for (int t = 0; t < 12; ++t) {
        const ushort* hin = (t & 1) ? h1 : h0;
        ushort* hout = (t & 1) ? h0 : h1;
        f32x4 acc[2][3] = {};

        // ---- burst: 64 coherent 8B loads (2 row-tiles x 16 slices x 16B) ----
        unsigned long long ha[2][16][2];
        if (t > 0) {
            #pragma unroll
            for (int sl = 0; sl < 16; ++sl) {
                const ushort* p0 = hin + rb0 + sl * 512 + aoff;
                const ushort* p1 = hin + rb1 + sl * 512 + aoff;
                ha[0][sl][0] = __hip_atomic_load((const unsigned long long*)p0,
                                                 __ATOMIC_RELAXED, __HIP_MEMORY_SCOPE_AGENT);
                ha[0][sl][1] = __hip_atomic_load((const unsigned long long*)(p0 + 4),
                                                 __ATOMIC_RELAXED, __HIP_MEMORY_SCOPE_AGENT);
                ha[1][sl][0] = __hip_atomic_load((const unsigned long long*)p1,
                                                 __ATOMIC_RELAXED, __HIP_MEMORY_SCOPE_AGENT);
                ha[1][sl][1] = __hip_atomic_load((const unsigned long long*)(p1 + 4),
                                                 __ATOMIC_RELAXED, __HIP_MEMORY_SCOPE_AGENT);
            }
        }

        // xW loads for this step (per row-tile; consumed in epilogue)
        uint2 xrv[2], xzv[2], xnv[2];
        #pragma unroll
        for (int rt = 0; rt < 2; ++rt) {
            const long xrow = ((long)(rt ? n1 : n0) * 12 + t) * 1536;
            xrv[rt] = *(const uint2*)(xW + xrow + f0);
            xzv[rt] = *(const uint2*)(xW + xrow + 512 + f0);
            xnv[rt] = *(const uint2*)(xW + xrow + 1024 + f0);
        }

        if (t > 0) {   // t==0: h=0 => hidden GEMM contributes 0
            #pragma unroll
            for (int kc = 0; kc < 8; ++kc) {
                const ushort* Bk = Bw + kc * (96 * 64);
                #pragma unroll
                for (int s = 0; s < 2; ++s) {
                    union { unsigned long long q[2]; bf16x8 v; } a0, a1;
                    a0.q[0] = ha[0][kc * 2 + s][0]; a0.q[1] = ha[0][kc * 2 + s][1];
                    a1.q[0] = ha[1][kc * 2 + s][0]; a1.q[1] = ha[1][kc * 2 + s][1];
                    const int sw = (((s << 2) + quad) ^ (ln & 7)) << 3;
                    #pragma unroll
                    for (int g = 0; g < 3; ++g) {
                        const int jt = g * 2 + cg;   // gate g, feature-half cg
                        const bf16x8 bh = *(const bf16x8*)(Bk + (jt * 16 + mrow) * 64 + sw);
                        acc[0][g] = __builtin_amdgcn_mfma_f32_16x16x32_bf16(bh, a0.v, acc[0][g], 0, 0, 0);
                        acc[1][g] = __builtin_amdgcn_mfma_f32_16x16x32_bf16(bh, a1.v, acc[1][g], 0, 0, 0);
                    }
                }
            }
        }

        // ---- epilogue: gates + state update per row-tile; fast exp2 path ----
        #pragma unroll
        for (int rt = 0; rt < 2; ++rt) {
            const ushort* xr = (const ushort*)&xrv[rt];
            const ushort* xz = (const ushort*)&xzv[rt];
            const ushort* xn = (const ushort*)&xnv[rt];
            const ushort* hp = (const ushort*)&hprev[rt];
            union { ushort u[4]; uint2 v; } o;
            #pragma unroll
            for (int r = 0; r < 4; ++r) {
                const float rr = fsigm(acc[rt][0][r] + b2f(xr[r]) + br[r]);
                const float zz = fsigm(acc[rt][1][r] + b2f(xz[r]) + bz[r]);
                const float nv = ftanh(b2f(xn[r]) + bni[r] + rr * (acc[rt][2][r] + bnh[r]));
                o.u[r] = f2b((1.f - zz) * nv + zz * b2f(hp[r]));
            }
            hprev[rt] = o.v;
        }

        if (t < 11) {
            // coherent h stores: 2 x 8B per thread (one per row-tile)
            union { uint2 v; unsigned long long q; } q0, q1;
            q0.v = hprev[0]; q1.v = hprev[1];
            __hip_atomic_store((unsigned long long*)&hout[sb0], q0.q,
                               __ATOMIC_RELAXED, __HIP_MEMORY_SCOPE_AGENT);
            __hip_atomic_store((unsigned long long*)&hout[sb1], q1.q,
                               __ATOMIC_RELAXED, __HIP_MEMORY_SCOPE_AGENT);
            asm volatile("s_waitcnt vmcnt(0)" ::: "memory");   // h stores at coherence point
            __syncthreads();
            if (tid == 0)
                __hip_atomic_fetch_add(cptr, 1u, __ATOMIC_RELAXED, __HIP_MEMORY_SCOPE_AGENT);
        }

        // G stores (overlap the barrier poll)
        *(uint2*)&G[((long)n0 * 12 + t) * 512 + f0] = hprev[0];
        *(uint2*)&G[((long)n1 * 12 + t) * 512 + f0] = hprev[1];

        if (t < 11) {
            if (tid == 0) {
                const unsigned tgt = (unsigned)(t + 1) * 16u;
                while (__hip_atomic_load(cptr, __ATOMIC_RELAXED, __HIP_MEMORY_SCOPE_AGENT) < tgt)
                    __builtin_amdgcn_s_sleep(1);
            }
            __syncthreads();
        }
    }
}

// =============== conversions ===============
__global__ __launch_bounds__(256) void cvt_x(const float* __restrict__ x, ushort* __restrict__ xb)
{
    const int idx = blockIdx.x * 256 + threadIdx.x;   // Mx*64
    const int m = idx >> 6, f8 = (idx & 63) << 3;
    const int n = m / 12, c = m - n * 12;
    const int b = n >> 2, w = n & 3;
    const float* src = x + (((b * 12 + c) * 4 + w) << 9) + f8;
    const float4 a = *(const float4*)src, q = *(const float4*)(src + 4);
    uint4 o;
    o.x = (unsigned)f2b(a.x) | ((unsigned)f2b(a.y) << 16);
    o.y = (unsigned)f2b(a.z) | ((unsigned)f2b(a.w) << 16);
    o.z = (unsigned)f2b(q.x) | ((unsigned)f2b(q.y) << 16);
    o.w = (unsigned)f2b(q.z) | ((unsigned)f2b(q.w) << 16);
    *(uint4*)(xb + (m << 9) + f8) = o;
}

// wih + whh fp32 -> bf16 (one launch)
__global__ __launch_bounds__(256) void cvt_w2(
    const float* __restrict__ wih, const float* __restrict__ whh,
    ushort* __restrict__ wihB, ushort* __restrict__ whhB)
{
    int bx = blockIdx.x;
    const float* s; ushort* d;
    if (bx < 384) { s = wih; d = wihB; } else { s = whh; d = whhB; bx -= 384; }
    const int e = (bx * 256 + threadIdx.x) << 3;
    const float4 a = *(const float4*)(s + e), q = *(const float4*)(s + e + 4);
    uint4 o;
    o.x = (unsigned)f2b(a.x) | ((unsigned)f2b(a.y) << 16);
    o.y = (unsigned)f2b(a.z) | ((unsigned)f2b(a.w) << 16);
    o.z = (unsigned)f2b(q.x) | ((unsigned)f2b(q.y) << 16);
    o.w = (unsigned)f2b(q.z) | ((unsigned)f2b(q.w) << 16);
    *(uint4*)(d + e) = o;
}

// 4 transpose-convert jobs in one launch: gw0, gw1, f1t, f2t
__global__ __launch_bounds__(256) void tcvt_all(
    const float* __restrict__ gcnw, const float* __restrict__ f1w, const float* __restrict__ f2w,
    ushort* __restrict__ gw0, ushort* __restrict__ gw1,
    ushort* __restrict__ f1t, ushort* __restrict__ f2t)
{
    int by = blockIdx.y;
    const float* src; ushort* dst; int R, C;
    if (by < 16)       { src = gcnw;          dst = gw0; R = 512;  C = 512; }
    else if (by < 32)  { src = gcnw + 262144; dst = gw1; R = 512;  C = 512; by -= 16; }
    else if (by < 224) { src = f1w;           dst = f1t; R = 6144; C = 512; by -= 32; }
    else               { src = f2w;           dst = f2t; R = 512;  C = 512; by -= 224; }
    __shared__ float tl[32][33];
    const int c0 = blockIdx.x * 32, r0 = by * 32;
    const int cx = threadIdx.x & 31, ry = threadIdx.x >> 5;
    #pragma unroll
    for (int k = 0; k < 4; ++k) tl[ry + k * 8][cx] = src[(long)(r0 + ry + k * 8) * C + c0 + cx];
    __syncthreads();
    #pragma unroll
    for (int k = 0; k < 4; ++k) dst[(long)(c0 + ry + k * 8) * R + r0 + cx] = f2b(tl[cx][ry + k * 8]);
}

// =============== graph-learning ===============
__global__ __launch_bounds__(256) void conv01(
    const ushort* __restrict__ G, const float* __restrict__ w0, const float* __restrict__ b0,
    const float* __restrict__ w1, const float* __restrict__ b1, float* __restrict__ y2)
{
    const int row = (blockIdx.x * 256 + threadIdx.x) >> 6;   // b*12+c
    const int lane = threadIdx.x & 63;
    const int b = row / 12, c = row - 12 * b;
    const float w00 = w0[0], w01 = w0[1], w02 = w0[2], w03 = w0[3], bb = b0[0];
    const ushort* gp = G + ((long)(b * 4) * 12 + c) * 512;
    float s = 0.f;
    for (int f = lane; f < 512; f += 64) {
        const float v = bb + b2f(gp[f]) * w00 + b2f(gp[6144 + f]) * w01
                      + b2f(gp[12288 + f]) * w02 + b2f(gp[18432 + f]) * w03;
        s += fmaxf(v, 0.f) * w1[f];
    }
    #pragma unroll
    for (int off = 32; off; off >>= 1) s += __shfl_down(s, off);
    if (lane == 0) y2[row] = fmaxf(s + b1[0], 0.f);
}

// conv2 + relu + batch-mean + adjacency -> Laplacian -> Chebyshev, single block
__global__ __launch_bounds__(256) void conv2_cheb(
    const float* __restrict__ y2, const float* __restrict__ w2,
    const float* __restrict__ b2, float* __restrict__ cheb)
{
    __shared__ float ys[6144];
    __shared__ float adj[144], deg[12], dhat[12], lap[144], T2[144];
    const int tid = threadIdx.x;
    for (int i = tid; i < 6144; i += 256) ys[i] = y2[i];
    __syncthreads();
    if (tid < 144) {
        float wk[12];
        #pragma unroll
        for (int c = 0; c < 12; ++c) wk[c] = w2[tid * 12 + c];
        const float bias = b2[tid];
        float s = 0.f;
        for (int b = 0; b < 512; ++b) {
            float v = bias;
            #pragma unroll
            for (int c = 0; c < 12; ++c) v += ys[b * 12 + c] * wk[c];
            s += fmaxf(v, 0.f);
        }
        adj[tid] = fmaxf(s * (1.f / 512.f), 0.f);
    }
    __syncthreads();
    if (tid < 12) {
        float s = 0.f;
        for (int j = 0; j < 12; ++j) s += adj[tid * 12 + j];
        deg[tid] = s; dhat[tid] = 1.f / (sqrtf(s) + 1e-7f);
    }
    __syncthreads();
    if (tid < 144) {
        const int i = tid / 12, j = tid % 12;
        const float as = 0.5f * (adj[i * 12 + j] + adj[j * 12 + i]);
        lap[tid] = dhat[i] * ((i == j ? deg[i] : 0.f) - as) * dhat[j];
    }
    __syncthreads();
    if (tid < 144) {
        const int i = tid / 12, j = tid % 12;
        float s = 0.f;
        for (int kk = 0; kk < 12; ++kk) s += lap[i * 12 + kk] * lap[kk * 12 + j];
        T2[tid] = 2.f * s;
    }
    __syncthreads();
    if (tid < 144) {
        const int i = tid / 12, j = tid % 12;
        float s = 0.f;
        for (int kk = 0; kk < 12; ++kk) s += lap[i * 12 + kk] * T2[kk * 12 + j];
        cheb[tid] = 0.f;
        cheb[144 + tid] = lap[tid];
        cheb[288 + tid] = T2[tid];
        cheb[432 + tid] = 2.f * s - lap[tid];
    }
}

// =============== GCN epilogues ===============
__global__ __launch_bounds__(256) void gcn_epi1(
    const ushort* __restrict__ S, const float* __restrict__ cheb,
    const float* __restrict__ gcnb, const ushort* __restrict__ G,
    ushort* __restrict__ H1)
{
    __shared__ float ch[576];
    const int tid = threadIdx.x;
    for (int i = tid; i < 576; i += 256) ch[i] = cheb[i];
    __syncthreads();
    const int idx = blockIdx.x * 256 + tid;
    const int f = idx & 511, bc = idx >> 9;
    const int b = bc / 12, c = bc - 12 * b;
    const float bias = gcnb[f];
    #pragma unroll
    for (int w = 0; w < 4; ++w) {
        float o = bias;
        const ushort* Sr = S + ((b * 4 + w) * 12) * 512 + f;
        const float* cw = ch + w * 144 + c * 12;
        #pragma unroll
        for (int j = 0; j < 12; ++j) o += cw[j] * b2f(Sr[j * 512]);
        const int gi = ((b * 4 + w) * 12 + c) * 512 + f;
        H1[gi] = f2b(fmaxf(o, 0.f) + b2f(G[gi]));
    }
}

__global__ __launch_bounds__(256) void gcn_epi2(
    const ushort* __restrict__ S, const float* __restrict__ cheb,
    const float* __restrict__ gcnb, const ushort* __restrict__ G,
    const ushort* __restrict__ H1, ushort* __restrict__ pooled)
{
    __shared__ float ch[576];
    const int tid = threadIdx.x;
    for (int i = tid; i < 576; i += 256) ch[i] = cheb[i];
    __syncthreads();
    const int idx = blockIdx.x * 256 + tid;
    const int f = idx & 511, bc = idx >> 9;
    const int b = bc / 12, c = bc - 12 * b;
    const float bias = gcnb[f];
    float acc = 0.f;
    #pragma unroll
    for (int w = 0; w < 4; ++w) {
        float o = bias;
        const ushort* Sr = S + ((b * 4 + w) * 12) * 512 + f;
        const float* cw = ch + w * 144 + c * 12;
        #pragma unroll
        for (int j = 0; j < 12; ++j) o += cw[j] * b2f(Sr[j * 512]);
        const int gi = ((b * 4 + w) * 12 + c) * 512 + f;
        acc += fmaxf(o, 0.f) + b2f(H1[gi]) + b2f(G[gi]);
    }
    pooled[idx] = f2b(acc);
}

// =============== head epilogues ===============
__global__ __launch_bounds__(256) void fc_epi(
    const float* __restrict__ part, int nsplit, const float* __restrict__ bias,
    const float* __restrict__ g, const float* __restrict__ be,
    const float* __restrict__ mu, const float* __restrict__ var,
    ushort* __restrict__ outb, float* __restrict__ outf)
{
    const int idx = blockIdx.x * 256 + threadIdx.x;
    const int c = idx & 511;
    float s = bias[c];
    for (int k = 0; k < nsplit; ++k) s += part[k * 262144 + idx];
    s = s >= 0.f ? s : 0.01f * s;
    s = (s - mu[c]) * rsqrtf(var[c] + 1e-5f) * g[c] + be[c];
    if (outb) outb[idx] = f2b(s); else outf[idx] = s;
}

__global__ __launch_bounds__(256) void fc3_kernel(
    const float* __restrict__ z2, const float* __restrict__ w3,
    const float* __restrict__ b3, float* __restrict__ out)
{
    const int idx = blockIdx.x * 256 + threadIdx.x;
    const int m = idx >> 2, nc = idx & 3;
    float s = b3[nc];
    const float* zr = z2 + m * 512;
    for (int k = 0; k < 512; ++k) s += zr[k] * w3[k * 4 + nc];
    out[idx] = s;
}

extern "C" void kernel_launch(void* const* d_in, const int* in_sizes, int n_in,
                              void* d_out, int out_size, void* d_ws, size_t ws_size,
                              hipStream_t stream)
{
    (void)in_sizes; (void)n_in; (void)out_size; (void)ws_size;
    const float* x    = (const float*)d_in[0];
    const float* wih  = (const float*)d_in[1];
    const float* whh  = (const float*)d_in[2];
    const float* bih  = (const float*)d_in[3];
    const float* bhh  = (const float*)d_in[4];
    const float* c0w  = (const float*)d_in[5];
    const float* c0b  = (const float*)d_in[6];
    const float* c1w  = (const float*)d_in[7];
    const float* c1b  = (const float*)d_in[8];
    const float* c2w  = (const float*)d_in[9];
    const float* c2b  = (const float*)d_in[10];
    const float* gcnw = (const float*)d_in[11];
    const float* gcnb = (const float*)d_in[12];
    const float* f1w  = (const float*)d_in[13];
    const float* f1b  = (const float*)d_in[14];
    const float* bn1g = (const float*)d_in[15];
    const float* bn1b = (const float*)d_in[16];
    const float* bn1m = (const float*)d_in[17];
    const float* bn1v = (const float*)d_in[18];
    const float* f2w  = (const float*)d_in[19];
    const float* f2b_ = (const float*)d_in[20];
    const float* bn2g = (const float*)d_in[21];
    const float* bn2b = (const float*)d_in[22];
    const float* bn2m = (const float*)d_in[23];
    const float* bn2v = (const float*)d_in[24];
    const float* f3w  = (const float*)d_in[25];
    const float* f3b  = (const float*)d_in[26];

    // ---- workspace layout (bytes), aliased; total ~112 MiB ----
    char* W = (char*)d_ws;
    ushort* xW     = (ushort*)(W + 0);             // 75.5 MB (dead after GRU)
    ushort* S      = (ushort*)(W + 0);             // 25.2 MB (alias xW)
    ushort* H1     = (ushort*)(W + 25165824);      // 25.2 MB (alias xW)
    ushort* pooled = (ushort*)(W + 50331648);      //  6.3 MB (alias xW)
    float*  z1p    = (float*)(W + 58720256);       // 16.8 MB (alias xW tail)
    float*  z2p    = z1p;                          //  4.2 MB (alias, after z1p consumed)
    ushort* xb     = (ushort*)(W + 75497472);      // 25.2 MB (dead after xW gemm)
    ushort* G      = (ushort*)(W + 75497472);      // 25.2 MB (alias xb)
    ushort* h0     = (ushort*)(W + 100663296);     //  2.1 MB (region layout)
    ushort* h1     = (ushort*)(W + 102760448);     //  2.1 MB (region layout)
    ushort* whhB   = (ushort*)(W + 104857600);     //  1.6 MB
    ushort* wihB   = (ushort*)(W + 106430464);     //  1.6 MB
    ushort* gw0    = (ushort*)(W + 108003328);     //  0.5 MB
    ushort* gw1    = (ushort*)(W + 108527616);     //  0.5 MB
    ushort* f1t    = (ushort*)(W + 109051904);     //  6.3 MB
    ushort* f2t    = (ushort*)(W + 115343360);     //  0.5 MB
    ushort* z1b    = (ushort*)(W + 115867648);     //  0.5 MB
    float*  z2     = (float*)(W + 116391936);      //  1.0 MB
    float*  y2     = (float*)(W + 117440512);      //  24.6 KB
    float*  chebb  = (float*)(W + 117465088);      //  2.3 KB
    unsigned* bar  = (unsigned*)(W + 117467392);   //  1 KB (16 groups x 64B)

    // ---- prep ----
    hipMemsetAsync(bar, 0, 1024, stream);
    cvt_x<<<(Mx * 64) / 256, 256, 0, stream>>>(x, xb);
    cvt_w2<<<768, 256, 0, stream>>>(wih, whh, wihB, whhB);
    tcvt_all<<<dim3(16, 240), 256, 0, stream>>>(gcnw, f1w, f2w, gw0, gw1, f1t, f2t);

    // ---- GRU: input gates hoisted into one big GEMM, then persistent recurrence ----
    mfma_gemm<<<dim3(2304, 1), 256, 0, stream>>>(
        xb, wihB, nullptr, xW, nullptr, 3 * Ff, Ff, Ff, 0, 192);
    gru_persist<<<256, 512, 0, stream>>>(xW, whhB, bih, bhh, h0, h1, G, bar);

    // ---- graph learning ----
    conv01<<<(Bb * Cc * 64) / 256, 256, 0, stream>>>(G, c0w, c0b, c1w, c1b, y2);
    conv2_cheb<<<1, 256, 0, stream>>>(y2, c2w, c2b, chebb);

    // ---- GCN layer 1 ----
    mfma_gemm<<<dim3(768, 1), 256, 0, stream>>>(
        G, gw0, nullptr, S, nullptr, Ff, Ff, Ff, 0, 192);
    gcn_epi1<<<(Bb * Cc * Ff) / 256, 256, 0, stream>>>(S, chebb, gcnb, G, H1);

    // ---- GCN layer 2 + pool ----
    mfma_gemm<<<dim3(768, 1), 256, 0, stream>>>(
        H1, gw1, nullptr, S, nullptr, Ff, Ff, Ff, 0, 192);
    gcn_epi2<<<(Bb * Cc * Ff) / 256, 256, 0, stream>>>(S, chebb, gcnb + Ff, G, H1, pooled);

    // ---- head ----
    mfma_gemm<<<dim3(16, 16), 256, 0, stream>>>(          // fc1 split-K 16
        pooled, f1t, z1p, nullptr, nullptr, 512, Cc * Ff, 384, 262144, 4);
    fc_epi<<<1024, 256, 0, stream>>>(z1p, 16, f1b, bn1g, bn1b, bn1m, bn1v, z1b, nullptr);
    mfma_gemm<<<dim3(16, 4), 256, 0, stream>>>(           // fc2 split-K 4
        z1b, f2t, z2p, nullptr, nullptr, 512, 512, 128, 262144, 4);
    fc_epi<<<1024, 256, 0, stream>>>(z2p, 4, f2b_, bn2g, bn2b, bn2m, bn2v, nullptr, z2);
    fc3_kernel<<<(Bb * 4) / 256, 256, 0, stream>>>(z2, f3w, f3b, (float*)d_out);
}

// Round 9
// 480.993 us; speedup vs baseline: 1.0016x; 1.0016x over previous
//
#include <hip/hip_runtime.h>
#include <cmath>

// ---- problem constants ----
constexpr int Bb  = 512;
constexpr int Cc  = 12;
constexpr int Ww  = 4;
constexpr int Ff  = 512;
constexpr int Mx  = Bb * Ww * Cc;   // 24576

typedef __attribute__((ext_vector_type(8))) short bf16x8;
typedef __attribute__((ext_vector_type(4))) float f32x4;

__device__ __forceinline__ float sigm(float v) { return 1.f / (1.f + expf(-v)); }
__device__ __forceinline__ float b2f(ushort u) { union { float f; unsigned i; } v; v.i = ((unsigned)u) << 16; return v.f; }
__device__ __forceinline__ ushort f2b(float f) {
    union { float f; unsigned i; } v; v.f = f;
    unsigned r = v.i + 0x7FFFu + ((v.i >> 16) & 1u);
    return (ushort)(r >> 16);
}
// fast branch-free transcendentals (v_exp_f32 is native 2^x; v_rcp_f32 ~1ulp)
__device__ __forceinline__ float fsigm(float v) {
    return __builtin_amdgcn_rcpf(1.f + __builtin_amdgcn_exp2f(v * -1.44269504f));
}
__device__ __forceinline__ float ftanh(float v) {
    return 1.f - 2.f * __builtin_amdgcn_rcpf(1.f + __builtin_amdgcn_exp2f(v * 2.88539008f));
}
__device__ __forceinline__ void async16(const ushort* g, ushort* l) {
    __builtin_amdgcn_global_load_lds(
        (const __attribute__((address_space(1))) unsigned int*)g,
        (__attribute__((address_space(3))) unsigned int*)l, 16, 0, 0);
}

// =============== generic bf16 MFMA GEMM ===============
// C[M,N] = A[M,K] @ Bt[N,K]^T.  Block 128x128, 4 waves.
__global__ __launch_bounds__(256) void mfma_gemm(
    const ushort* __restrict__ A, const ushort* __restrict__ Bt,
    float* __restrict__ Cf, ushort* __restrict__ Cb,
    const float* __restrict__ colBias,
    int N, int K, int kLen, int MN, int gridY)
{
    __shared__ ushort As[128 * 64], Bs[128 * 64];
    const int tid = threadIdx.x;
    const int ln = tid & 63, wv = tid >> 6;
    const int l = blockIdx.x;
    const int by = l % gridY, bx = l / gridY, bz = blockIdx.y;
    const int srow = ln >> 3;
    const int kslot = (ln & 7) ^ srow;
    const int rowA0 = by * 128 + wv * 32;
    const int rowB0 = bx * 128 + wv * 32;
    const ushort* ga = A  + (long)(rowA0 + srow) * K + bz * kLen + kslot * 8;
    const ushort* gb = Bt + (long)(rowB0 + srow) * K + bz * kLen + kslot * 8;
    ushort* la = As + wv * 32 * 64;
    ushort* lb = Bs + wv * 32 * 64;
    const int rbase = (wv >> 1) * 64, cbase = (wv & 1) * 64;
    const int mrow = ln & 15, quad = ln >> 4;

    f32x4 acc[4][4] = {};

    for (int kc = 0; kc < kLen; kc += 64) {
        #pragma unroll
        for (int i = 0; i < 4; ++i) {
            async16(ga + (long)(i * 8) * K, la + i * 8 * 64);
            async16(gb + (long)(i * 8) * K, lb + i * 8 * 64);
        }
        ga += 64; gb += 64;
        __syncthreads();
        #pragma unroll
        for (int s = 0; s < 2; ++s) {
            const int sw = (((s << 2) + quad) ^ (ln & 7)) << 3;
            bf16x8 af[4], bf[4];
            #pragma unroll
            for (int i = 0; i < 4; ++i)
                af[i] = *(const bf16x8*)(As + (rbase + i * 16 + mrow) * 64 + sw);
            #pragma unroll
            for (int j = 0; j < 4; ++j)
                bf[j] = *(const bf16x8*)(Bs + (cbase + j * 16 + mrow) * 64 + sw);
            #pragma unroll
            for (int i = 0; i < 4; ++i)
                #pragma unroll
                for (int j = 0; j < 4; ++j)
                    acc[i][j] = __builtin_amdgcn_mfma_f32_16x16x32_bf16(bf[j], af[i], acc[i][j], 0, 0, 0);
        }
        __syncthreads();
    }

    const int gr0 = by * 128 + rbase + mrow;
    const int gc0 = bx * 128 + cbase + quad * 4;
    if (Cb) {
        #pragma unroll
        for (int i = 0; i < 4; ++i) {
            const long rowoff = (long)(gr0 + i * 16) * N;
            #pragma unroll
            for (int j = 0; j < 4; ++j) {
                float c0 = 0.f, c1 = 0.f, c2 = 0.f, c3 = 0.f;
                if (colBias) {
                    const float4 cb4 = *(const float4*)(colBias + gc0 + j * 16);
                    c0 = cb4.x; c1 = cb4.y; c2 = cb4.z; c3 = cb4.w;
                }
                union { ushort u[4]; uint2 v; } pk;
                pk.u[0] = f2b(acc[i][j][0] + c0);
                pk.u[1] = f2b(acc[i][j][1] + c1);
                pk.u[2] = f2b(acc[i][j][2] + c2);
                pk.u[3] = f2b(acc[i][j][3] + c3);
                *(uint2*)&Cb[rowoff + gc0 + j * 16] = pk.v;
            }
        }
    } else {
        float* Co = Cf + (long)bz * MN;
        #pragma unroll
        for (int i = 0; i < 4; ++i) {
            const long rowoff = (long)(gr0 + i * 16) * N;
            #pragma unroll
            for (int j = 0; j < 4; ++j)
                *(f32x4*)&Co[rowoff + gc0 + j * 16] = acc[i][j];
        }
    }
}

// =============== persistent GRU recurrence (v8: exchange through G, write-once) ===============
// v6 partition (8 waves x 16 rows x 96 cols; measured best) with the h exchange
// routed through G itself: G[n,t,f] = h_t[n,f], every (n,t) address written
// exactly ONCE. Producer: 2 x 8B agent-scope stores into G (write-through to
// L3) -> vmcnt(0) -> flag. Consumer: PLAIN cacheable 16B loads of the t-1
// slice -- first touch of each line happens after the flag, and kernel-start
// acquire invalidated L1/L2, so stale caching is impossible (no dependence on
// XCD mapping for correctness). Group blocks sharing an XCD serve 15/16 of
// the loads from L2 instead of L3 (v6 re-pulled 32 MB/step from L3 because
// agent-scope loads bypass L2). h0/h1 ping-pong buffers eliminated.
__global__ __launch_bounds__(512, 1) void gru_persist(
    const ushort* __restrict__ xW, const ushort* __restrict__ whhB,
    const float* __restrict__ bih, const float* __restrict__ bhh,
    ushort* __restrict__ G, unsigned* __restrict__ bar)
{
    __shared__ ushort Bw[8 * 96 * 64];     // 96 KB: Whh slice, [kc][96][64] k-swizzled
    const int tid = threadIdx.x, ln = tid & 63, wv = tid >> 6;
    const int mb = blockIdx.x & 15, fb = blockIdx.x >> 4;
    const int srow = ln >> 3, kslot = (ln & 7) ^ srow;
    const int mrow = ln & 15, quad = ln >> 4;

    // ---- load Whh slice once: rows g*512 + fb*32 + fc, layout [kc][96][64] ----
    #pragma unroll
    for (int i = 0; i < 12; ++i) {
        const int rg = i * 8 + wv;                 // 0..95
        const int kc6 = rg / 12, rgi = rg - kc6 * 12;
        const int r0 = rgi * 8, r = r0 + srow;
        const int g = r >> 5, fc = r & 31;
        async16(whhB + (long)(g * 512 + fb * 32 + fc) * 512 + kc6 * 64 + kslot * 8,
                Bw + (kc6 * 96 + r0) * 64);
    }

    // ---- hoist biases (invariant across steps) ----
    float br[2][4], bz[2][4], bni[2][4], bnh[2][4];
    #pragma unroll
    for (int ft = 0; ft < 2; ++ft) {
        const int f0 = fb * 32 + ft * 16 + quad * 4;
        const float4 bir = *(const float4*)(bih + f0);
        const float4 biz = *(const float4*)(bih + 512 + f0);
        const float4 bin = *(const float4*)(bih + 1024 + f0);
        const float4 bhr = *(const float4*)(bhh + f0);
        const float4 bhz = *(const float4*)(bhh + 512 + f0);
        const float4 bhn = *(const float4*)(bhh + 1024 + f0);
        br[ft][0] = bir.x + bhr.x; br[ft][1] = bir.y + bhr.y; br[ft][2] = bir.z + bhr.z; br[ft][3] = bir.w + bhr.w;
        bz[ft][0] = biz.x + bhz.x; bz[ft][1] = biz.y + bhz.y; bz[ft][2] = biz.z + bhz.z; bz[ft][3] = biz.w + bhz.w;
        bni[ft][0] = bin.x; bni[ft][1] = bin.y; bni[ft][2] = bin.z; bni[ft][3] = bin.w;
        bnh[ft][0] = bhn.x; bnh[ft][1] = bhn.y; bnh[ft][2] = bhn.z; bnh[ft][3] = bhn.w;
    }
    __syncthreads();   // Bw resident (compiler drains vmcnt before s_barrier); read-only after

    const int n = mb * 128 + wv * 16 + mrow;
    const long grow = (long)n * 12;        // G row base (rows are (n*12+t))
    unsigned* cptr = bar + mb * 16;        // 64B-spaced per-group counter
    const int f0 = fb * 32 + quad * 4;     // producer feature base (ft=0; ft=1 at +16)

    uint2 hprev[2]; hprev[0].x = 0u; hprev[0].y = 0u; hprev[1] = hprev[0];

    for (int t = 0; t < 12; ++t) {
        f32x4 acc[6] = {};

        // ---- consumer: 16 PLAIN 16B loads of the t-1 slice of G ----
        uint4 ha4[16];
        if (t > 0) {
            const ushort* gsrc = G + (grow + (t - 1)) * 512 + quad * 8;
            #pragma unroll
            for (int sl = 0; sl < 16; ++sl)       // sl = kc*2+s; feats sl*32+quad*8..+7
                ha4[sl] = *(const uint4*)(gsrc + sl * 32);
        }

        // xW loads for this step (independent; consumed in epilogue)
        const long xrow = (grow + t) * 1536;
        uint2 xrv[2], xzv[2], xnv[2];
        #pragma unroll
        for (int ft = 0; ft < 2; ++ft) {
            const int ff = fb * 32 + ft * 16 + quad * 4;
            xrv[ft] = *(const uint2*)(xW + xrow + ff);
            xzv[ft] = *(const uint2*)(xW + xrow + 512 + ff);
            xnv[ft] = *(const uint2*)(xW + xrow + 1024 + ff);
        }

        if (t > 0) {   // t==0: h=0 => hidden GEMM contributes 0
            #pragma unroll
            for (int kc = 0; kc < 8; ++kc) {
                const ushort* Bk = Bw + kc * (96 * 64);
                #pragma unroll
                for (int s = 0; s < 2; ++s) {
                    union { uint4 u4; bf16x8 v; } af;
                    af.u4 = ha4[kc * 2 + s];
                    const int sw = (((s << 2) + quad) ^ (ln & 7)) << 3;
                    #pragma unroll
                    for (int jt = 0; jt < 6; ++jt) {
                        const bf16x8 bh = *(const bf16x8*)(Bk + (jt * 16 + mrow) * 64 + sw);
                        acc[jt] = __builtin_amdgcn_mfma_f32_16x16x32_bf16(bh, af.v, acc[jt], 0, 0, 0);
                    }
                }
            }
        }

        // ---- epilogue: gates + state update; h_prev from registers; fast exp2 path ----
        #pragma unroll
        for (int ft = 0; ft < 2; ++ft) {
            const ushort* xr = (const ushort*)&xrv[ft];
            const ushort* xz = (const ushort*)&xzv[ft];
            const ushort* xn = (const ushort*)&xnv[ft];
            const ushort* hp = (const ushort*)&hprev[ft];
            union { ushort u[4]; uint2 v; } o;
            #pragma unroll
            for (int r = 0; r < 4; ++r) {
                const float rr = fsigm(acc[ft][r] + b2f(xr[r]) + br[ft][r]);
                const float zz = fsigm(acc[2 + ft][r] + b2f(xz[r]) + bz[ft][r]);
                const float nv = ftanh(b2f(xn[r]) + bni[ft][r] + rr * (acc[4 + ft][r] + bnh[ft][r]));
                o.u[r] = f2b((1.f - zz) * nv + zz * b2f(hp[r]));
            }
            hprev[ft] = o.v;
        }

        ushort* gdst = G + (grow + t) * 512 + f0;
        if (t < 11) {
            // exchange stores: agent-scope write-through to L3, then flag
            union { uint2 v; unsigned long long q; } q0, q1;
            q0.v = hprev[0]; q1.v = hprev[1];
            __hip_atomic_store((unsigned long long*)gdst, q0.q,
                               __ATOMIC_RELAXED, __HIP_MEMORY_SCOPE_AGENT);
            __hip_atomic_store((unsigned long long*)(gdst + 16), q1.q,
                               __ATOMIC_RELAXED, __HIP_MEMORY_SCOPE_AGENT);
            asm volatile("s_waitcnt vmcnt(0)" ::: "memory");   // stores at coherence point
            __syncthreads();
            if (tid == 0)
                __hip_atomic_fetch_add(cptr, 1u, __ATOMIC_RELAXED, __HIP_MEMORY_SCOPE_AGENT);
            if (tid == 0) {
                const unsigned tgt = (unsigned)(t + 1) * 16u;
                while (__hip_atomic_load(cptr, __ATOMIC_RELAXED, __HIP_MEMORY_SCOPE_AGENT) < tgt)
                    __builtin_amdgcn_s_sleep(1);
            }
            __syncthreads();
        } else {
            // last step: no in-kernel consumer; plain fire-and-forget stores
            *(uint2*)gdst = hprev[0];
            *(uint2*)(gdst + 16) = hprev[1];
        }
    }
}

// =============== conversions ===============
__global__ __launch_bounds__(256) void cvt_x(const float* __restrict__ x, ushort* __restrict__ xb)
{
    const int idx = blockIdx.x * 256 + threadIdx.x;   // Mx*64
    const int m = idx >> 6, f8 = (idx & 63) << 3;
    const int n = m / 12, c = m - n * 12;
    const int b = n >> 2, w = n & 3;
    const float* src = x + (((b * 12 + c) * 4 + w) << 9) + f8;
    const float4 a = *(const float4*)src, q = *(const float4*)(src + 4);
    uint4 o;
    o.x = (unsigned)f2b(a.x) | ((unsigned)f2b(a.y) << 16);
    o.y = (unsigned)f2b(a.z) | ((unsigned)f2b(a.w) << 16);
    o.z = (unsigned)f2b(q.x) | ((unsigned)f2b(q.y) << 16);
    o.w = (unsigned)f2b(q.z) | ((unsigned)f2b(q.w) << 16);
    *(uint4*)(xb + (m << 9) + f8) = o;
}

// wih + whh fp32 -> bf16 (one launch)
__global__ __launch_bounds__(256) void cvt_w2(
    const float* __restrict__ wih, const float* __restrict__ whh,
    ushort* __restrict__ wihB, ushort* __restrict__ whhB)
{
    int bx = blockIdx.x;
    const float* s; ushort* d;
    if (bx < 384) { s = wih; d = wihB; } else { s = whh; d = whhB; bx -= 384; }
    const int e = (bx * 256 + threadIdx.x) << 3;
    const float4 a = *(const float4*)(s + e), q = *(const float4*)(s + e + 4);
    uint4 o;
    o.x = (unsigned)f2b(a.x) | ((unsigned)f2b(a.y) << 16);
    o.y = (unsigned)f2b(a.z) | ((unsigned)f2b(a.w) << 16);
    o.z = (unsigned)f2b(q.x) | ((unsigned)f2b(q.y) << 16);
    o.w = (unsigned)f2b(q.z) | ((unsigned)f2b(q.w) << 16);
    *(uint4*)(d + e) = o;
}

// 4 transpose-convert jobs in one launch: gw0, gw1, f1t, f2t
__global__ __launch_bounds__(256) void tcvt_all(
    const float* __restrict__ gcnw, const float* __restrict__ f1w, const float* __restrict__ f2w,
    ushort* __restrict__ gw0, ushort* __restrict__ gw1,
    ushort* __restrict__ f1t, ushort* __restrict__ f2t)
{
    int by = blockIdx.y;
    const float* src; ushort* dst; int R, C;
    if (by < 16)       { src = gcnw;          dst = gw0; R = 512;  C = 512; }
    else if (by < 32)  { src = gcnw + 262144; dst = gw1; R = 512;  C = 512; by -= 16; }
    else if (by < 224) { src = f1w;           dst = f1t; R = 6144; C = 512; by -= 32; }
    else               { src = f2w;           dst = f2t; R = 512;  C = 512; by -= 224; }
    __shared__ float tl[32][33];
    const int c0 = blockIdx.x * 32, r0 = by * 32;
    const int cx = threadIdx.x & 31, ry = threadIdx.x >> 5;
    #pragma unroll
    for (int k = 0; k < 4; ++k) tl[ry + k * 8][cx] = src[(long)(r0 + ry + k * 8) * C + c0 + cx];
    __syncthreads();
    #pragma unroll
    for (int k = 0; k < 4; ++k) dst[(long)(c0 + ry + k * 8) * R + r0 + cx] = f2b(tl[cx][ry + k * 8]);
}

// =============== graph-learning ===============
__global__ __launch_bounds__(256) void conv01(
    const ushort* __restrict__ G, const float* __restrict__ w0, const float* __restrict__ b0,
    const float* __restrict__ w1, const float* __restrict__ b1, float* __restrict__ y2)
{
    const int row = (blockIdx.x * 256 + threadIdx.x) >> 6;   // b*12+c
    const int lane = threadIdx.x & 63;
    const int b = row / 12, c = row - 12 * b;
    const float w00 = w0[0], w01 = w0[1], w02 = w0[2], w03 = w0[3], bb = b0[0];
    const ushort* gp = G + ((long)(b * 4) * 12 + c) * 512;
    float s = 0.f;
    for (int f = lane; f < 512; f += 64) {
        const float v = bb + b2f(gp[f]) * w00 + b2f(gp[6144 + f]) * w01
                      + b2f(gp[12288 + f]) * w02 + b2f(gp[18432 + f]) * w03;
        s += fmaxf(v, 0.f) * w1[f];
    }
    #pragma unroll
    for (int off = 32; off; off >>= 1) s += __shfl_down(s, off);
    if (lane == 0) y2[row] = fmaxf(s + b1[0], 0.f);
}

// conv2 + relu + batch-mean + adjacency -> Laplacian -> Chebyshev, single block
__global__ __launch_bounds__(256) void conv2_cheb(
    const float* __restrict__ y2, const float* __restrict__ w2,
    const float* __restrict__ b2, float* __restrict__ cheb)
{
    __shared__ float ys[6144];
    __shared__ float adj[144], deg[12], dhat[12], lap[144], T2[144];
    const int tid = threadIdx.x;
    for (int i = tid; i < 6144; i += 256) ys[i] = y2[i];
    __syncthreads();
    if (tid < 144) {
        float wk[12];
        #pragma unroll
        for (int c = 0; c < 12; ++c) wk[c] = w2[tid * 12 + c];
        const float bias = b2[tid];
        float s = 0.f;
        for (int b = 0; b < 512; ++b) {
            float v = bias;
            #pragma unroll
            for (int c = 0; c < 12; ++c) v += ys[b * 12 + c] * wk[c];
            s += fmaxf(v, 0.f);
        }
        adj[tid] = fmaxf(s * (1.f / 512.f), 0.f);
    }
    __syncthreads();
    if (tid < 12) {
        float s = 0.f;
        for (int j = 0; j < 12; ++j) s += adj[tid * 12 + j];
        deg[tid] = s; dhat[tid] = 1.f / (sqrtf(s) + 1e-7f);
    }
    __syncthreads();
    if (tid < 144) {
        const int i = tid / 12, j = tid % 12;
        const float as = 0.5f * (adj[i * 12 + j] + adj[j * 12 + i]);
        lap[tid] = dhat[i] * ((i == j ? deg[i] : 0.f) - as) * dhat[j];
    }
    __syncthreads();
    if (tid < 144) {
        const int i = tid / 12, j = tid % 12;
        float s = 0.f;
        for (int kk = 0; kk < 12; ++kk) s += lap[i * 12 + kk] * lap[kk * 12 + j];
        T2[tid] = 2.f * s;
    }
    __syncthreads();
    if (tid < 144) {
        const int i = tid / 12, j = tid % 12;
        float s = 0.f;
        for (int kk = 0; kk < 12; ++kk) s += lap[i * 12 + kk] * T2[kk * 12 + j];
        cheb[tid] = 0.f;
        cheb[144 + tid] = lap[tid];
        cheb[288 + tid] = T2[tid];
        cheb[432 + tid] = 2.f * s - lap[tid];
    }
}

// =============== GCN epilogues ===============
__global__ __launch_bounds__(256) void gcn_epi1(
    const ushort* __restrict__ S, const float* __restrict__ cheb,
    const float* __restrict__ gcnb, const ushort* __restrict__ G,
    ushort* __restrict__ H1)
{
    __shared__ float ch[576];
    const int tid = threadIdx.x;
    for (int i = tid; i < 576; i += 256) ch[i] = cheb[i];
    __syncthreads();
    const int idx = blockIdx.x * 256 + tid;
    const int f = idx & 511, bc = idx >> 9;
    const int b = bc / 12, c = bc - 12 * b;
    const float bias = gcnb[f];
    #pragma unroll
    for (int w = 0; w < 4; ++w) {
        float o = bias;
        const ushort* Sr = S + ((b * 4 + w) * 12) * 512 + f;
        const float* cw = ch + w * 144 + c * 12;
        #pragma unroll
        for (int j = 0; j < 12; ++j) o += cw[j] * b2f(Sr[j * 512]);
        const int gi = ((b * 4 + w) * 12 + c) * 512 + f;
        H1[gi] = f2b(fmaxf(o, 0.f) + b2f(G[gi]));
    }
}

__global__ __launch_bounds__(256) void gcn_epi2(
    const ushort* __restrict__ S, const float* __restrict__ cheb,
    const float* __restrict__ gcnb, const ushort* __restrict__ G,
    const ushort* __restrict__ H1, ushort* __restrict__ pooled)
{
    __shared__ float ch[576];
    const int tid = threadIdx.x;
    for (int i = tid; i < 576; i += 256) ch[i] = cheb[i];
    __syncthreads();
    const int idx = blockIdx.x * 256 + tid;
    const int f = idx & 511, bc = idx >> 9;
    const int b = bc / 12, c = bc - 12 * b;
    const float bias = gcnb[f];
    float acc = 0.f;
    #pragma unroll
    for (int w = 0; w < 4; ++w) {
        float o = bias;
        const ushort* Sr = S + ((b * 4 + w) * 12) * 512 + f;
        const float* cw = ch + w * 144 + c * 12;
        #pragma unroll
        for (int j = 0; j < 12; ++j) o += cw[j] * b2f(Sr[j * 512]);
        const int gi = ((b * 4 + w) * 12 + c) * 512 + f;
        acc += fmaxf(o, 0.f) + b2f(H1[gi]) + b2f(G[gi]);
    }
    pooled[idx] = f2b(acc);
}

// =============== head epilogues ===============
__global__ __launch_bounds__(256) void fc_epi(
    const float* __restrict__ part, int nsplit, const float* __restrict__ bias,
    const float* __restrict__ g, const float* __restrict__ be,
    const float* __restrict__ mu, const float* __restrict__ var,
    ushort* __restrict__ outb, float* __restrict__ outf)
{
    const int idx = blockIdx.x * 256 + threadIdx.x;
    const int c = idx & 511;
    float s = bias[c];
    for (int k = 0; k < nsplit; ++k) s += part[k * 262144 + idx];
    s = s >= 0.f ? s : 0.01f * s;
    s = (s - mu[c]) * rsqrtf(var[c] + 1e-5f) * g[c] + be[c];
    if (outb) outb[idx] = f2b(s); else outf[idx] = s;
}

__global__ __launch_bounds__(256) void fc3_kernel(
    const float* __restrict__ z2, const float* __restrict__ w3,
    const float* __restrict__ b3, float* __restrict__ out)
{
    const int idx = blockIdx.x * 256 + threadIdx.x;
    const int m = idx >> 2, nc = idx & 3;
    float s = b3[nc];
    const float* zr = z2 + m * 512;
    for (int k = 0; k < 512; ++k) s += zr[k] * w3[k * 4 + nc];
    out[idx] = s;
}

extern "C" void kernel_launch(void* const* d_in, const int* in_sizes, int n_in,
                              void* d_out, int out_size, void* d_ws, size_t ws_size,
                              hipStream_t stream)
{
    (void)in_sizes; (void)n_in; (void)out_size; (void)ws_size;
    const float* x    = (const float*)d_in[0];
    const float* wih  = (const float*)d_in[1];
    const float* whh  = (const float*)d_in[2];
    const float* bih  = (const float*)d_in[3];
    const float* bhh  = (const float*)d_in[4];
    const float* c0w  = (const float*)d_in[5];
    const float* c0b  = (const float*)d_in[6];
    const float* c1w  = (const float*)d_in[7];
    const float* c1b  = (const float*)d_in[8];
    const float* c2w  = (const float*)d_in[9];
    const float* c2b  = (const float*)d_in[10];
    const float* gcnw = (const float*)d_in[11];
    const float* gcnb = (const float*)d_in[12];
    const float* f1w  = (const float*)d_in[13];
    const float* f1b  = (const float*)d_in[14];
    const float* bn1g = (const float*)d_in[15];
    const float* bn1b = (const float*)d_in[16];
    const float* bn1m = (const float*)d_in[17];
    const float* bn1v = (const float*)d_in[18];
    const float* f2w  = (const float*)d_in[19];
    const float* f2b_ = (const float*)d_in[20];
    const float* bn2g = (const float*)d_in[21];
    const float* bn2b = (const float*)d_in[22];
    const float* bn2m = (const float*)d_in[23];
    const float* bn2v = (const float*)d_in[24];
    const float* f3w  = (const float*)d_in[25];
    const float* f3b  = (const float*)d_in[26];

    // ---- workspace layout (bytes), aliased; total ~112 MiB ----
    char* W = (char*)d_ws;
    ushort* xW     = (ushort*)(W + 0);             // 75.5 MB (dead after GRU)
    ushort* S      = (ushort*)(W + 0);             // 25.2 MB (alias xW)
    ushort* H1     = (ushort*)(W + 25165824);      // 25.2 MB (alias xW)
    ushort* pooled = (ushort*)(W + 50331648);      //  6.3 MB (alias xW)
    float*  z1p    = (float*)(W + 58720256);       // 16.8 MB (alias xW tail)
    float*  z2p    = z1p;                          //  4.2 MB (alias, after z1p consumed)
    ushort* xb     = (ushort*)(W + 75497472);      // 25.2 MB (dead after xW gemm)
    ushort* G      = (ushort*)(W + 75497472);      // 25.2 MB (alias xb; GRU exchange + output)
    ushort* whhB   = (ushort*)(W + 104857600);     //  1.6 MB
    ushort* wihB   = (ushort*)(W + 106430464);     //  1.6 MB
    ushort* gw0    = (ushort*)(W + 108003328);     //  0.5 MB
    ushort* gw1    = (ushort*)(W + 108527616);     //  0.5 MB
    ushort* f1t    = (ushort*)(W + 109051904);     //  6.3 MB
    ushort* f2t    = (ushort*)(W + 115343360);     //  0.5 MB
    ushort* z1b    = (ushort*)(W + 115867648);     //  0.5 MB
    float*  z2     = (float*)(W + 116391936);      //  1.0 MB
    float*  y2     = (float*)(W + 117440512);      //  24.6 KB
    float*  chebb  = (float*)(W + 117465088);      //  2.3 KB
    unsigned* bar  = (unsigned*)(W + 117467392);   //  1 KB (16 groups x 64B)

    // ---- prep ----
    hipMemsetAsync(bar, 0, 1024, stream);
    cvt_x<<<(Mx * 64) / 256, 256, 0, stream>>>(x, xb);
    cvt_w2<<<768, 256, 0, stream>>>(wih, whh, wihB, whhB);
    tcvt_all<<<dim3(16, 240), 256, 0, stream>>>(gcnw, f1w, f2w, gw0, gw1, f1t, f2t);

    // ---- GRU: input gates hoisted into one big GEMM, then persistent recurrence ----
    mfma_gemm<<<dim3(2304, 1), 256, 0, stream>>>(
        xb, wihB, nullptr, xW, nullptr, 3 * Ff, Ff, Ff, 0, 192);
    gru_persist<<<256, 512, 0, stream>>>(xW, whhB, bih, bhh, G, bar);

    // ---- graph learning ----
    conv01<<<(Bb * Cc * 64) / 256, 256, 0, stream>>>(G, c0w, c0b, c1w, c1b, y2);
    conv2_cheb<<<1, 256, 0, stream>>>(y2, c2w, c2b, chebb);

    // ---- GCN layer 1 ----
    mfma_gemm<<<dim3(768, 1), 256, 0, stream>>>(
        G, gw0, nullptr, S, nullptr, Ff, Ff, Ff, 0, 192);
    gcn_epi1<<<(Bb * Cc * Ff) / 256, 256, 0, stream>>>(S, chebb, gcnb, G, H1);

    // ---- GCN layer 2 + pool ----
    mfma_gemm<<<dim3(768, 1), 256, 0, stream>>>(
        H1, gw1, nullptr, S, nullptr, Ff, Ff, Ff, 0, 192);
    gcn_epi2<<<(Bb * Cc * Ff) / 256, 256, 0, stream>>>(S, chebb, gcnb + Ff, G, H1, pooled);

    // ---- head ----
    mfma_gemm<<<dim3(16, 16), 256, 0, stream>>>(          // fc1 split-K 16
        pooled, f1t, z1p, nullptr, nullptr, 512, Cc * Ff, 384, 262144, 4);
    fc_epi<<<1024, 256, 0, stream>>>(z1p, 16, f1b, bn1g, bn1b, bn1m, bn1v, z1b, nullptr);
    mfma_gemm<<<dim3(16, 4), 256, 0, stream>>>(           // fc2 split-K 4
        z1b, f2t, z2p, nullptr, nullptr, 512, 512, 128, 262144, 4);
    fc_epi<<<1024, 256, 0, stream>>>(z2p, 4, f2b_, bn2g, bn2b, bn2m, bn2v, nullptr, z2);
    fc3_kernel<<<(Bb * 4) / 256, 256, 0, stream>>>(z2, f3w, f3b, (float*)d_out);
}

// Round 10
// 445.308 us; speedup vs baseline: 1.0819x; 1.0801x over previous
//
#include <hip/hip_runtime.h>
#include <cmath>

// ---- problem constants ----
constexpr int Bb  = 512;
constexpr int Cc  = 12;
constexpr int Ww  = 4;
constexpr int Ff  = 512;
constexpr int Mx  = Bb * Ww * Cc;   // 24576

typedef __attribute__((ext_vector_type(8))) short bf16x8;
typedef __attribute__((ext_vector_type(4))) float f32x4;

__device__ __forceinline__ float sigm(float v) { return 1.f / (1.f + expf(-v)); }
__device__ __forceinline__ float b2f(ushort u) { union { float f; unsigned i; } v; v.i = ((unsigned)u) << 16; return v.f; }
__device__ __forceinline__ ushort f2b(float f) {
    union { float f; unsigned i; } v; v.f = f;
    unsigned r = v.i + 0x7FFFu + ((v.i >> 16) & 1u);
    return (ushort)(r >> 16);
}
// fast branch-free transcendentals (v_exp_f32 is native 2^x; v_rcp_f32 ~1ulp)
__device__ __forceinline__ float fsigm(float v) {
    return __builtin_amdgcn_rcpf(1.f + __builtin_amdgcn_exp2f(v * -1.44269504f));
}
__device__ __forceinline__ float ftanh(float v) {
    return 1.f - 2.f * __builtin_amdgcn_rcpf(1.f + __builtin_amdgcn_exp2f(v * 2.88539008f));
}
__device__ __forceinline__ void async16(const ushort* g, ushort* l) {
    __builtin_amdgcn_global_load_lds(
        (const __attribute__((address_space(1))) unsigned int*)g,
        (__attribute__((address_space(3))) unsigned int*)l, 16, 0, 0);
}

// =============== generic bf16 MFMA GEMM ===============
// C[M,N] = A[M,K] @ Bt[N,K]^T.  Block 128x128, 4 waves.
__global__ __launch_bounds__(256) void mfma_gemm(
    const ushort* __restrict__ A, const ushort* __restrict__ Bt,
    float* __restrict__ Cf, ushort* __restrict__ Cb,
    const float* __restrict__ colBias,
    int N, int K, int kLen, int MN, int gridY)
{
    __shared__ ushort As[128 * 64], Bs[128 * 64];
    const int tid = threadIdx.x;
    const int ln = tid & 63, wv = tid >> 6;
    const int l = blockIdx.x;
    const int by = l % gridY, bx = l / gridY, bz = blockIdx.y;
    const int srow = ln >> 3;
    const int kslot = (ln & 7) ^ srow;
    const int rowA0 = by * 128 + wv * 32;
    const int rowB0 = bx * 128 + wv * 32;
    const ushort* ga = A  + (long)(rowA0 + srow) * K + bz * kLen + kslot * 8;
    const ushort* gb = Bt + (long)(rowB0 + srow) * K + bz * kLen + kslot * 8;
    ushort* la = As + wv * 32 * 64;
    ushort* lb = Bs + wv * 32 * 64;
    const int rbase = (wv >> 1) * 64, cbase = (wv & 1) * 64;
    const int mrow = ln & 15, quad = ln >> 4;

    f32x4 acc[4][4] = {};

    for (int kc = 0; kc < kLen; kc += 64) {
        #pragma unroll
        for (int i = 0; i < 4; ++i) {
            async16(ga + (long)(i * 8) * K, la + i * 8 * 64);
            async16(gb + (long)(i * 8) * K, lb + i * 8 * 64);
        }
        ga += 64; gb += 64;
        __syncthreads();
        #pragma unroll
        for (int s = 0; s < 2; ++s) {
            const int sw = (((s << 2) + quad) ^ (ln & 7)) << 3;
            bf16x8 af[4], bf[4];
            #pragma unroll
            for (int i = 0; i < 4; ++i)
                af[i] = *(const bf16x8*)(As + (rbase + i * 16 + mrow) * 64 + sw);
            #pragma unroll
            for (int j = 0; j < 4; ++j)
                bf[j] = *(const bf16x8*)(Bs + (cbase + j * 16 + mrow) * 64 + sw);
            #pragma unroll
            for (int i = 0; i < 4; ++i)
                #pragma unroll
                for (int j = 0; j < 4; ++j)
                    acc[i][j] = __builtin_amdgcn_mfma_f32_16x16x32_bf16(bf[j], af[i], acc[i][j], 0, 0, 0);
        }
        __syncthreads();
    }

    const int gr0 = by * 128 + rbase + mrow;
    const int gc0 = bx * 128 + cbase + quad * 4;
    if (Cb) {
        #pragma unroll
        for (int i = 0; i < 4; ++i) {
            const long rowoff = (long)(gr0 + i * 16) * N;
            #pragma unroll
            for (int j = 0; j < 4; ++j) {
                float c0 = 0.f, c1 = 0.f, c2 = 0.f, c3 = 0.f;
                if (colBias) {
                    const float4 cb4 = *(const float4*)(colBias + gc0 + j * 16);
                    c0 = cb4.x; c1 = cb4.y; c2 = cb4.z; c3 = cb4.w;
                }
                union { ushort u[4]; uint2 v; } pk;
                pk.u[0] = f2b(acc[i][j][0] + c0);
                pk.u[1] = f2b(acc[i][j][1] + c1);
                pk.u[2] = f2b(acc[i][j][2] + c2);
                pk.u[3] = f2b(acc[i][j][3] + c3);
                *(uint2*)&Cb[rowoff + gc0 + j * 16] = pk.v;
            }
        }
    } else {
        float* Co = Cf + (long)bz * MN;
        #pragma unroll
        for (int i = 0; i < 4; ++i) {
            const long rowoff = (long)(gr0 + i * 16) * N;
            #pragma unroll
            for (int j = 0; j < 4; ++j)
                *(f32x4*)&Co[rowoff + gc0 + j * 16] = acc[i][j];
        }
    }
}

// =============== persistent GRU recurrence (v6: measured best, 91.5us) ===============
// Register-direct A fragments, region-layout h exchange, read-only LDS Bw,
// block-level cumulative barrier with a SINGLE tid-0 poller per block
// (other waves parked at s_barrier -- keeps the coherence fabric quiet).
// Fast exp2/rcp transcendental epilogue.
__global__ __launch_bounds__(512, 1) void gru_persist(
    const ushort* __restrict__ xW, const ushort* __restrict__ whhB,
    const float* __restrict__ bih, const float* __restrict__ bhh,
    ushort* __restrict__ h0, ushort* __restrict__ h1,
    ushort* __restrict__ G, unsigned* __restrict__ bar)
{
    __shared__ ushort Bw[8 * 96 * 64];     // 96 KB: Whh slice, [kc][96][64] k-swizzled
    const int tid = threadIdx.x, ln = tid & 63, wv = tid >> 6;
    const int mb = blockIdx.x & 15, fb = blockIdx.x >> 4;
    const int srow = ln >> 3, kslot = (ln & 7) ^ srow;
    const int mrow = ln & 15, quad = ln >> 4;

    // ---- load Whh slice once: rows g*512 + fb*32 + fc, layout [kc][96][64] ----
    #pragma unroll
    for (int i = 0; i < 12; ++i) {
        const int rg = i * 8 + wv;                 // 0..95
        const int kc6 = rg / 12, rgi = rg - kc6 * 12;
        const int r0 = rgi * 8, r = r0 + srow;
        const int g = r >> 5, fc = r & 31;
        async16(whhB + (long)(g * 512 + fb * 32 + fc) * 512 + kc6 * 64 + kslot * 8,
                Bw + (kc6 * 96 + r0) * 64);
    }

    // ---- hoist biases (invariant across steps) ----
    float br[2][4], bz[2][4], bni[2][4], bnh[2][4];
    #pragma unroll
    for (int ft = 0; ft < 2; ++ft) {
        const int f0 = fb * 32 + ft * 16 + quad * 4;
        const float4 bir = *(const float4*)(bih + f0);
        const float4 biz = *(const float4*)(bih + 512 + f0);
        const float4 bin = *(const float4*)(bih + 1024 + f0);
        const float4 bhr = *(const float4*)(bhh + f0);
        const float4 bhz = *(const float4*)(bhh + 512 + f0);
        const float4 bhn = *(const float4*)(bhh + 1024 + f0);
        br[ft][0] = bir.x + bhr.x; br[ft][1] = bir.y + bhr.y; br[ft][2] = bir.z + bhr.z; br[ft][3] = bir.w + bhr.w;
        bz[ft][0] = biz.x + bhz.x; bz[ft][1] = biz.y + bhz.y; bz[ft][2] = biz.z + bhz.z; bz[ft][3] = biz.w + bhz.w;
        bni[ft][0] = bin.x; bni[ft][1] = bin.y; bni[ft][2] = bin.z; bni[ft][3] = bin.w;
        bnh[ft][0] = bhn.x; bnh[ft][1] = bhn.y; bnh[ft][2] = bhn.z; bnh[ft][3] = bhn.w;
    }
    __syncthreads();   // Bw resident (compiler drains vmcnt before s_barrier); read-only after

    const int n = mb * 128 + wv * 16 + mrow;
    unsigned* cptr = bar + mb * 16;        // 64B-spaced per-group counter

    // consumer a-load geometry: region R(mb,wv,fb') = ((mb*8+wv)*16+fb')*512 ushorts
    const int rbase0 = ((mb * 8 + wv) * 16) * 512;
    const int aoff = (quad >> 1) * 256 + mrow * 16 + (quad & 1) * 8;
    // producer store: region fb, + ft*256 + mrow*16 + quad*4
    const int sbase = ((mb * 8 + wv) * 16 + fb) * 512 + mrow * 16 + quad * 4;

    uint2 hprev[2]; hprev[0].x = 0u; hprev[0].y = 0u; hprev[1] = hprev[0];

    for (int t = 0; t < 12; ++t) {
        const ushort* hin = (t & 1) ? h1 : h0;
        ushort* hout = (t & 1) ? h0 : h1;
        f32x4 acc[6] = {};

        // ---- burst: 32 coherent 8B loads (16 slices x 16B) direct to registers ----
        unsigned long long ha[16][2];
        if (t > 0) {
            #pragma unroll
            for (int sl = 0; sl < 16; ++sl) {    // sl = fb' = kc*2+s
                const ushort* p = hin + rbase0 + sl * 512 + aoff;
                ha[sl][0] = __hip_atomic_load((const unsigned long long*)p,
                                              __ATOMIC_RELAXED, __HIP_MEMORY_SCOPE_AGENT);
                ha[sl][1] = __hip_atomic_load((const unsigned long long*)(p + 4),
                                              __ATOMIC_RELAXED, __HIP_MEMORY_SCOPE_AGENT);
            }
        }

        // xW loads for this step (issued after the a-burst; consumed in epilogue)
        const long xrow = ((long)n * 12 + t) * 1536;
        uint2 xrv[2], xzv[2], xnv[2];
        #pragma unroll
        for (int ft = 0; ft < 2; ++ft) {
            const int f0 = fb * 32 + ft * 16 + quad * 4;
            xrv[ft] = *(const uint2*)(xW + xrow + f0);
            xzv[ft] = *(const uint2*)(xW + xrow + 512 + f0);
            xnv[ft] = *(const uint2*)(xW + xrow + 1024 + f0);
        }

        if (t > 0) {   // t==0: h=0 => hidden GEMM contributes 0
            #pragma unroll
            for (int kc = 0; kc < 8; ++kc) {
                const ushort* Bk = Bw + kc * (96 * 64);
                #pragma unroll
                for (int s = 0; s < 2; ++s) {
                    union { unsigned long long q[2]; bf16x8 v; } af;
                    af.q[0] = ha[kc * 2 + s][0];
                    af.q[1] = ha[kc * 2 + s][1];
                    const int sw = (((s << 2) + quad) ^ (ln & 7)) << 3;
                    #pragma unroll
                    for (int jt = 0; jt < 6; ++jt) {
                        const bf16x8 bh = *(const bf16x8*)(Bk + (jt * 16 + mrow) * 64 + sw);
                        acc[jt] = __builtin_amdgcn_mfma_f32_16x16x32_bf16(bh, af.v, acc[jt], 0, 0, 0);
                    }
                }
            }
        }

        // ---- epilogue: gates + state update; h_prev from registers; fast exp2 path ----
        #pragma unroll
        for (int ft = 0; ft < 2; ++ft) {
            const ushort* xr = (const ushort*)&xrv[ft];
            const ushort* xz = (const ushort*)&xzv[ft];
            const ushort* xn = (const ushort*)&xnv[ft];
            const ushort* hp = (const ushort*)&hprev[ft];
            union { ushort u[4]; uint2 v; } o;
            #pragma unroll
            for (int r = 0; r < 4; ++r) {
                const float rr = fsigm(acc[ft][r] + b2f(xr[r]) + br[ft][r]);
                const float zz = fsigm(acc[2 + ft][r] + b2f(xz[r]) + bz[ft][r]);
                const float nv = ftanh(b2f(xn[r]) + bni[ft][r] + rr * (acc[4 + ft][r] + bnh[ft][r]));
                o.u[r] = f2b((1.f - zz) * nv + zz * b2f(hp[r]));
            }
            hprev[ft] = o.v;
        }

        if (t < 11) {
            // coherent h stores: 2 x 8B per thread, wave-contiguous 512B per ft
            union { uint2 v; unsigned long long q; } q0, q1;
            q0.v = hprev[0]; q1.v = hprev[1];
            __hip_atomic_store((unsigned long long*)&hout[sbase], q0.q,
                               __ATOMIC_RELAXED, __HIP_MEMORY_SCOPE_AGENT);
            __hip_atomic_store((unsigned long long*)&hout[sbase + 256], q1.q,
                               __ATOMIC_RELAXED, __HIP_MEMORY_SCOPE_AGENT);
            asm volatile("s_waitcnt vmcnt(0)" ::: "memory");   // h stores at coherence point
            __syncthreads();
            if (tid == 0)
                __hip_atomic_fetch_add(cptr, 1u, __ATOMIC_RELAXED, __HIP_MEMORY_SCOPE_AGENT);
        }

        // G stores (overlap the barrier poll)
        {
            const int f0 = fb * 32 + quad * 4;
            *(uint2*)&G[((long)n * 12 + t) * 512 + f0] = hprev[0];
            *(uint2*)&G[((long)n * 12 + t) * 512 + f0 + 16] = hprev[1];
        }

        if (t < 11) {
            if (tid == 0) {
                const unsigned tgt = (unsigned)(t + 1) * 16u;
                while (__hip_atomic_load(cptr, __ATOMIC_RELAXED, __HIP_MEMORY_SCOPE_AGENT) < tgt)
                    __builtin_amdgcn_s_sleep(1);
            }
            __syncthreads();
        }
    }
}

// =============== conversions ===============
__global__ __launch_bounds__(256) void cvt_x(const float* __restrict__ x, ushort* __restrict__ xb)
{
    const int idx = blockIdx.x * 256 + threadIdx.x;   // Mx*64
    const int m = idx >> 6, f8 = (idx & 63) << 3;
    const int n = m / 12, c = m - n * 12;
    const int b = n >> 2, w = n & 3;
    const float* src = x + (((b * 12 + c) * 4 + w) << 9) + f8;
    const float4 a = *(const float4*)src, q = *(const float4*)(src + 4);
    uint4 o;
    o.x = (unsigned)f2b(a.x) | ((unsigned)f2b(a.y) << 16);
    o.y = (unsigned)f2b(a.z) | ((unsigned)f2b(a.w) << 16);
    o.z = (unsigned)f2b(q.x) | ((unsigned)f2b(q.y) << 16);
    o.w = (unsigned)f2b(q.z) | ((unsigned)f2b(q.w) << 16);
    *(uint4*)(xb + (m << 9) + f8) = o;
}

// wih + whh fp32 -> bf16 (one launch)
__global__ __launch_bounds__(256) void cvt_w2(
    const float* __restrict__ wih, const float* __restrict__ whh,
    ushort* __restrict__ wihB, ushort* __restrict__ whhB)
{
    int bx = blockIdx.x;
    const float* s; ushort* d;
    if (bx < 384) { s = wih; d = wihB; } else { s = whh; d = whhB; bx -= 384; }
    const int e = (bx * 256 + threadIdx.x) << 3;
    const float4 a = *(const float4*)(s + e), q = *(const float4*)(s + e + 4);
    uint4 o;
    o.x = (unsigned)f2b(a.x) | ((unsigned)f2b(a.y) << 16);
    o.y = (unsigned)f2b(a.z) | ((unsigned)f2b(a.w) << 16);
    o.z = (unsigned)f2b(q.x) | ((unsigned)f2b(q.y) << 16);
    o.w = (unsigned)f2b(q.z) | ((unsigned)f2b(q.w) << 16);
    *(uint4*)(d + e) = o;
}

// 4 transpose-convert jobs in one launch: gw0, gw1, f1t, f2t
__global__ __launch_bounds__(256) void tcvt_all(
    const float* __restrict__ gcnw, const float* __restrict__ f1w, const float* __restrict__ f2w,
    ushort* __restrict__ gw0, ushort* __restrict__ gw1,
    ushort* __restrict__ f1t, ushort* __restrict__ f2t)
{
    int by = blockIdx.y;
    const float* src; ushort* dst; int R, C;
    if (by < 16)       { src = gcnw;          dst = gw0; R = 512;  C = 512; }
    else if (by < 32)  { src = gcnw + 262144; dst = gw1; R = 512;  C = 512; by -= 16; }
    else if (by < 224) { src = f1w;           dst = f1t; R = 6144; C = 512; by -= 32; }
    else               { src = f2w;           dst = f2t; R = 512;  C = 512; by -= 224; }
    __shared__ float tl[32][33];
    const int c0 = blockIdx.x * 32, r0 = by * 32;
    const int cx = threadIdx.x & 31, ry = threadIdx.x >> 5;
    #pragma unroll
    for (int k = 0; k < 4; ++k) tl[ry + k * 8][cx] = src[(long)(r0 + ry + k * 8) * C + c0 + cx];
    __syncthreads();
    #pragma unroll
    for (int k = 0; k < 4; ++k) dst[(long)(c0 + ry + k * 8) * R + r0 + cx] = f2b(tl[cx][ry + k * 8]);
}

// =============== graph-learning ===============
__global__ __launch_bounds__(256) void conv01(
    const ushort* __restrict__ G, const float* __restrict__ w0, const float* __restrict__ b0,
    const float* __restrict__ w1, const float* __restrict__ b1, float* __restrict__ y2)
{
    const int row = (blockIdx.x * 256 + threadIdx.x) >> 6;   // b*12+c
    const int lane = threadIdx.x & 63;
    const int b = row / 12, c = row - 12 * b;
    const float w00 = w0[0], w01 = w0[1], w02 = w0[2], w03 = w0[3], bb = b0[0];
    const ushort* gp = G + ((long)(b * 4) * 12 + c) * 512;
    float s = 0.f;
    for (int f = lane; f < 512; f += 64) {
        const float v = bb + b2f(gp[f]) * w00 + b2f(gp[6144 + f]) * w01
                      + b2f(gp[12288 + f]) * w02 + b2f(gp[18432 + f]) * w03;
        s += fmaxf(v, 0.f) * w1[f];
    }
    #pragma unroll
    for (int off = 32; off; off >>= 1) s += __shfl_down(s, off);
    if (lane == 0) y2[row] = fmaxf(s + b1[0], 0.f);
}

// conv2 + relu + batch-mean + adjacency -> Laplacian -> Chebyshev, single block
__global__ __launch_bounds__(256) void conv2_cheb(
    const float* __restrict__ y2, const float* __restrict__ w2,
    const float* __restrict__ b2, float* __restrict__ cheb)
{
    __shared__ float ys[6144];
    __shared__ float adj[144], deg[12], dhat[12], lap[144], T2[144];
    const int tid = threadIdx.x;
    for (int i = tid; i < 6144; i += 256) ys[i] = y2[i];
    __syncthreads();
    if (tid < 144) {
        float wk[12];
        #pragma unroll
        for (int c = 0; c < 12; ++c) wk[c] = w2[tid * 12 + c];
        const float bias = b2[tid];
        float s = 0.f;
        for (int b = 0; b < 512; ++b) {
            float v = bias;
            #pragma unroll
            for (int c = 0; c < 12; ++c) v += ys[b * 12 + c] * wk[c];
            s += fmaxf(v, 0.f);
        }
        adj[tid] = fmaxf(s * (1.f / 512.f), 0.f);
    }
    __syncthreads();
    if (tid < 12) {
        float s = 0.f;
        for (int j = 0; j < 12; ++j) s += adj[tid * 12 + j];
        deg[tid] = s; dhat[tid] = 1.f / (sqrtf(s) + 1e-7f);
    }
    __syncthreads();
    if (tid < 144) {
        const int i = tid / 12, j = tid % 12;
        const float as = 0.5f * (adj[i * 12 + j] + adj[j * 12 + i]);
        lap[tid] = dhat[i] * ((i == j ? deg[i] : 0.f) - as) * dhat[j];
    }
    __syncthreads();
    if (tid < 144) {
        const int i = tid / 12, j = tid % 12;
        float s = 0.f;
        for (int kk = 0; kk < 12; ++kk) s += lap[i * 12 + kk] * lap[kk * 12 + j];
        T2[tid] = 2.f * s;
    }
    __syncthreads();
    if (tid < 144) {
        const int i = tid / 12, j = tid % 12;
        float s = 0.f;
        for (int kk = 0; kk < 12; ++kk) s += lap[i * 12 + kk] * T2[kk * 12 + j];
        cheb[tid] = 0.f;
        cheb[144 + tid] = lap[tid];
        cheb[288 + tid] = T2[tid];
        cheb[432 + tid] = 2.f * s - lap[tid];
    }
}

// =============== GCN epilogues (v2: c-in-registers, S/G read once) ===============
// One thread owns one (group g=b*4+w, feature f) and computes ALL 12 c outputs:
// the 12 S-rows are loaded once into registers instead of 12x per c.
// epi1: grid 4096 = 2048 groups x 2 f-chunks, block 256.
__global__ __launch_bounds__(256) void gcn_epi1(
    const ushort* __restrict__ S, const float* __restrict__ cheb,
    const float* __restrict__ gcnb, const ushort* __restrict__ G,
    ushort* __restrict__ H1)
{
    __shared__ float ch[576];
    const int tid = threadIdx.x;
    for (int i = tid; i < 576; i += 256) ch[i] = cheb[i];
    __syncthreads();
    const int g = blockIdx.x >> 1;                 // b*4+w
    const int w = g & 3;
    const int f = (blockIdx.x & 1) * 256 + tid;
    const float bias = gcnb[f];
    float sv[12];
    #pragma unroll
    for (int j = 0; j < 12; ++j) sv[j] = b2f(S[((long)(g * 12 + j)) * 512 + f]);
    const float* cw0 = ch + w * 144;
    #pragma unroll
    for (int c = 0; c < 12; ++c) {
        float o = bias;
        const float* cw = cw0 + c * 12;
        #pragma unroll
        for (int j = 0; j < 12; ++j) o += cw[j] * sv[j];
        const long gi = ((long)(g * 12 + c)) * 512 + f;
        H1[gi] = f2b(fmaxf(o, 0.f) + b2f(G[gi]));
    }
}

// epi2: grid 1024 = 512 b x 2 f-chunks, block 256; w-loop inside, acc[12] regs.
__global__ __launch_bounds__(256) void gcn_epi2(
    const ushort* __restrict__ S, const float* __restrict__ cheb,
    const float* __restrict__ gcnb, const ushort* __restrict__ G,
    const ushort* __restrict__ H1, ushort* __restrict__ pooled)
{
    __shared__ float ch[576];
    const int tid = threadIdx.x;
    for (int i = tid; i < 576; i += 256) ch[i] = cheb[i];
    __syncthreads();
    const int b = blockIdx.x >> 1;
    const int f = (blockIdx.x & 1) * 256 + tid;
    const float bias = gcnb[f];
    float acc[12];
    #pragma unroll
    for (int c = 0; c < 12; ++c) acc[c] = 0.f;
    #pragma unroll
    for (int w = 0; w < 4; ++w) {
        const int g = b * 4 + w;
        float sv[12];
        #pragma unroll
        for (int j = 0; j < 12; ++j) sv[j] = b2f(S[((long)(g * 12 + j)) * 512 + f]);
        const float* cw0 = ch + w * 144;
        #pragma unroll
        for (int c = 0; c < 12; ++c) {
            float o = bias;
            const float* cw = cw0 + c * 12;
            #pragma unroll
            for (int j = 0; j < 12; ++j) o += cw[j] * sv[j];
            const long gi = ((long)(g * 12 + c)) * 512 + f;
            acc[c] += fmaxf(o, 0.f) + b2f(H1[gi]) + b2f(G[gi]);
        }
    }
    #pragma unroll
    for (int c = 0; c < 12; ++c)
        pooled[((long)(b * 12 + c)) * 512 + f] = f2b(acc[c]);
}

// =============== head epilogues ===============
__global__ __launch_bounds__(256) void fc_epi(
    const float* __restrict__ part, int nsplit, const float* __restrict__ bias,
    const float* __restrict__ g, const float* __restrict__ be,
    const float* __restrict__ mu, const float* __restrict__ var,
    ushort* __restrict__ outb, float* __restrict__ outf)
{
    const int idx = blockIdx.x * 256 + threadIdx.x;
    const int c = idx & 511;
    float s = bias[c];
    for (int k = 0; k < nsplit; ++k) s += part[k * 262144 + idx];
    s = s >= 0.f ? s : 0.01f * s;
    s = (s - mu[c]) * rsqrtf(var[c] + 1e-5f) * g[c] + be[c];
    if (outb) outb[idx] = f2b(s); else outf[idx] = s;
}

__global__ __launch_bounds__(256) void fc3_kernel(
    const float* __restrict__ z2, const float* __restrict__ w3,
    const float* __restrict__ b3, float* __restrict__ out)
{
    const int idx = blockIdx.x * 256 + threadIdx.x;
    const int m = idx >> 2, nc = idx & 3;
    float s = b3[nc];
    const float* zr = z2 + m * 512;
    for (int k = 0; k < 512; ++k) s += zr[k] * w3[k * 4 + nc];
    out[idx] = s;
}

extern "C" void kernel_launch(void* const* d_in, const int* in_sizes, int n_in,
                              void* d_out, int out_size, void* d_ws, size_t ws_size,
                              hipStream_t stream)
{
    (void)in_sizes; (void)n_in; (void)out_size; (void)ws_size;
    const float* x    = (const float*)d_in[0];
    const float* wih  = (const float*)d_in[1];
    const float* whh  = (const float*)d_in[2];
    const float* bih  = (const float*)d_in[3];
    const float* bhh  = (const float*)d_in[4];
    const float* c0w  = (const float*)d_in[5];
    const float* c0b  = (const float*)d_in[6];
    const float* c1w  = (const float*)d_in[7];
    const float* c1b  = (const float*)d_in[8];
    const float* c2w  = (const float*)d_in[9];
    const float* c2b  = (const float*)d_in[10];
    const float* gcnw = (const float*)d_in[11];
    const float* gcnb = (const float*)d_in[12];
    const float* f1w  = (const float*)d_in[13];
    const float* f1b  = (const float*)d_in[14];
    const float* bn1g = (const float*)d_in[15];
    const float* bn1b = (const float*)d_in[16];
    const float* bn1m = (const float*)d_in[17];
    const float* bn1v = (const float*)d_in[18];
    const float* f2w  = (const float*)d_in[19];
    const float* f2b_ = (const float*)d_in[20];
    const float* bn2g = (const float*)d_in[21];
    const float* bn2b = (const float*)d_in[22];
    const float* bn2m = (const float*)d_in[23];
    const float* bn2v = (const float*)d_in[24];
    const float* f3w  = (const float*)d_in[25];
    const float* f3b  = (const float*)d_in[26];

    // ---- workspace layout (bytes), aliased; total ~112 MiB ----
    char* W = (char*)d_ws;
    ushort* xW     = (ushort*)(W + 0);             // 75.5 MB (dead after GRU)
    ushort* S      = (ushort*)(W + 0);             // 25.2 MB (alias xW)
    ushort* H1     = (ushort*)(W + 25165824);      // 25.2 MB (alias xW)
    ushort* pooled = (ushort*)(W + 50331648);      //  6.3 MB (alias xW)
    float*  z1p    = (float*)(W + 58720256);       // 16.8 MB (alias xW tail)
    float*  z2p    = z1p;                          //  4.2 MB (alias, after z1p consumed)
    ushort* xb     = (ushort*)(W + 75497472);      // 25.2 MB (dead after xW gemm)
    ushort* G      = (ushort*)(W + 75497472);      // 25.2 MB (alias xb)
    ushort* h0     = (ushort*)(W + 100663296);     //  2.1 MB (region layout)
    ushort* h1     = (ushort*)(W + 102760448);     //  2.1 MB (region layout)
    ushort* whhB   = (ushort*)(W + 104857600);     //  1.6 MB
    ushort* wihB   = (ushort*)(W + 106430464);     //  1.6 MB
    ushort* gw0    = (ushort*)(W + 108003328);     //  0.5 MB
    ushort* gw1    = (ushort*)(W + 108527616);     //  0.5 MB
    ushort* f1t    = (ushort*)(W + 109051904);     //  6.3 MB
    ushort* f2t    = (ushort*)(W + 115343360);     //  0.5 MB
    ushort* z1b    = (ushort*)(W + 115867648);     //  0.5 MB
    float*  z2     = (float*)(W + 116391936);      //  1.0 MB
    float*  y2     = (float*)(W + 117440512);      //  24.6 KB
    float*  chebb  = (float*)(W + 117465088);      //  2.3 KB
    unsigned* bar  = (unsigned*)(W + 117467392);   //  1 KB (16 groups x 64B)

    // ---- prep ----
    hipMemsetAsync(bar, 0, 1024, stream);
    cvt_x<<<(Mx * 64) / 256, 256, 0, stream>>>(x, xb);
    cvt_w2<<<768, 256, 0, stream>>>(wih, whh, wihB, whhB);
    tcvt_all<<<dim3(16, 240), 256, 0, stream>>>(gcnw, f1w, f2w, gw0, gw1, f1t, f2t);

    // ---- GRU: input gates hoisted into one big GEMM, then persistent recurrence ----
    mfma_gemm<<<dim3(2304, 1), 256, 0, stream>>>(
        xb, wihB, nullptr, xW, nullptr, 3 * Ff, Ff, Ff, 0, 192);
    gru_persist<<<256, 512, 0, stream>>>(xW, whhB, bih, bhh, h0, h1, G, bar);

    // ---- graph learning ----
    conv01<<<(Bb * Cc * 64) / 256, 256, 0, stream>>>(G, c0w, c0b, c1w, c1b, y2);
    conv2_cheb<<<1, 256, 0, stream>>>(y2, c2w, c2b, chebb);

    // ---- GCN layer 1 ----
    mfma_gemm<<<dim3(768, 1), 256, 0, stream>>>(
        G, gw0, nullptr, S, nullptr, Ff, Ff, Ff, 0, 192);
    gcn_epi1<<<4096, 256, 0, stream>>>(S, chebb, gcnb, G, H1);

    // ---- GCN layer 2 + pool ----
    mfma_gemm<<<dim3(768, 1), 256, 0, stream>>>(
        H1, gw1, nullptr, S, nullptr, Ff, Ff, Ff, 0, 192);
    gcn_epi2<<<1024, 256, 0, stream>>>(S, chebb, gcnb + Ff, G, H1, pooled);

    // ---- head ----
    mfma_gemm<<<dim3(16, 16), 256, 0, stream>>>(          // fc1 split-K 16
        pooled, f1t, z1p, nullptr, nullptr, 512, Cc * Ff, 384, 262144, 4);
    fc_epi<<<1024, 256, 0, stream>>>(z1p, 16, f1b, bn1g, bn1b, bn1m, bn1v, z1b, nullptr);
    mfma_gemm<<<dim3(16, 4), 256, 0, stream>>>(           // fc2 split-K 4
        z1b, f2t, z2p, nullptr, nullptr, 512, 512, 128, 262144, 4);
    fc_epi<<<1024, 256, 0, stream>>>(z2p, 4, f2b_, bn2g, bn2b, bn2m, bn2v, nullptr, z2);
    fc3_kernel<<<(Bb * 4) / 256, 256, 0, stream>>>(z2, f3w, f3b, (float*)d_out);
}